// Round 2
// baseline (2619.255 us; speedup 1.0000x reference)
//
#include <hip/hip_runtime.h>
#include <hip/hip_bf16.h>

#define N_NODES 200000
#define N_GRAPHS 1024
#define D 16
#define NEDGE 6400000

#define BNODES 256                 // nodes per bucket: bucket = dst >> 8
#define NBUK 782                   // ceil(200000/256)
#define NCH 640                    // edge chunks
#define ECHUNK 10000               // NEDGE / NCH (exact)
#define CAP 9216                   // bucket slab capacity (mean 8192, sd ~90 -> 11 sigma)
#define GBLK 12500                 // t1 blocks: 16 nodes x 16 lanes

// ---- pA (fused R+L): sort one 10000-edge chunk by bucket in LDS, then append each
//      bucket-run directly into the global per-bucket slab (atomic run allocation,
//      coalesced run writes). Output: bucket-grouped, unsorted within bucket. ----
__global__ __launch_bounds__(1024) void pA(
        const int* __restrict__ srcR, const int* __restrict__ dstR,
        const int* __restrict__ srcL, const int* __restrict__ dstL,
        unsigned int* __restrict__ slabR, unsigned int* __restrict__ slabL,
        int* __restrict__ gcurR, int* __restrict__ gcurL) {
    const int* src = blockIdx.y ? srcL : srcR;
    const int* dst = blockIdx.y ? dstL : dstR;
    unsigned int* slab = blockIdx.y ? slabL : slabR;
    int* gcur = blockIdx.y ? gcurL : gcurR;

    __shared__ unsigned int stage[ECHUNK];      // 40 KB
    __shared__ unsigned short stageB[ECHUNK];   // 20 KB (bucket id per staged entry)
    __shared__ int lh[NBUK];                    // counts -> append offset (gb - lex)
    __shared__ int lcur[NBUK];
    __shared__ int lex[NBUK + 1];
    __shared__ int wsum[16];
    int t = threadIdx.x;
    int wave = t >> 6, lane = t & 63;
    int base = blockIdx.x * ECHUNK;

    for (int k = t; k < NBUK; k += 1024) lh[k] = 0;
    __syncthreads();
    for (int e = t; e < ECHUNK; e += 1024)
        atomicAdd(&lh[((unsigned int)dst[base + e]) >> 8], 1);
    __syncthreads();

    int v = (t < NBUK) ? lh[t] : 0;
    int x = v;
#pragma unroll
    for (int d0 = 1; d0 < 64; d0 <<= 1) {
        int y = __shfl_up(x, d0, 64);
        if (lane >= d0) x += y;
    }
    if (lane == 63) wsum[wave] = x;
    __syncthreads();
    if (wave == 0 && lane < 16) {
        int s = wsum[lane];
#pragma unroll
        for (int d0 = 1; d0 < 16; d0 <<= 1) {
            int y = __shfl_up(s, d0, 64);
            if (lane >= d0) s += y;
        }
        wsum[lane] = s;
    }
    __syncthreads();
    int excl = x - v + (wave ? wsum[wave - 1] : 0);
    if (t <= NBUK) lex[t] = excl;
    if (t < NBUK) lcur[t] = excl;
    // allocate this chunk's run in each bucket's global slab region
    if (t < NBUK) {
        int gb = v ? atomicAdd(&gcur[t], v) : 0;
        lh[t] = gb - excl;                      // append offset: global = k*CAP + lh[k] + e
    }
    __syncthreads();

    for (int e = t; e < ECHUNK; e += 1024) {
        int d = dst[base + e];
        int s = src[base + e];
        int buk = ((unsigned int)d) >> 8;
        int pos = atomicAdd(&lcur[buk], 1);
        stage[pos] = ((unsigned int)(d & 255) << 18) | (unsigned int)s;
        stageB[pos] = (unsigned short)buk;
    }
    __syncthreads();
    for (int e = t; e < ECHUNK; e += 1024) {
        int k = stageB[e];
        int off = lh[k] + e;                    // gb + (e - lex[k])
        slab[(size_t)k * CAP + off] = stage[e];
    }
}

// ---- pD: per-bucket degree histogram -> dis (needed by t1) ----
__global__ __launch_bounds__(256) void pD(
        const unsigned int* __restrict__ slabR, const unsigned int* __restrict__ slabL,
        const int* __restrict__ gcurR, const int* __restrict__ gcurL,
        float* __restrict__ disR, float* __restrict__ disL) {
    int y = blockIdx.y;
    const unsigned int* slab = y ? slabL : slabR;
    const int* gcur = y ? gcurL : gcurR;
    float* dis = y ? disL : disR;

    __shared__ int hcnt[BNODES];
    int t = threadIdx.x;
    int b = blockIdx.x;
    hcnt[t] = 0;
    __syncthreads();
    int cnt = gcur[b]; if (cnt > CAP) cnt = CAP;
    const unsigned int* sl = slab + (size_t)b * CAP;
    for (int i = t; i < cnt; i += 256)
        atomicAdd(&hcnt[__builtin_nontemporal_load(sl + i) >> 18], 1);
    __syncthreads();
    int node = (b << 8) + t;
    if (node < N_NODES) dis[node] = rsqrtf((float)hcnt[t] + 1.0f);
}

// ---- t1 (fused R+L): hs1[i,j] = bf16( (emb[ids[i]] @ W1)[j] * dis[i] ) ----
__global__ __launch_bounds__(256) void t1_kernel(
        const int* __restrict__ idsR, const int* __restrict__ idsL,
        const float* __restrict__ emb, const float* __restrict__ W,
        const float* __restrict__ disR, const float* __restrict__ disL,
        __hip_bfloat16* __restrict__ hsR, __hip_bfloat16* __restrict__ hsL) {
    int y = blockIdx.y;
    const int* ids = y ? idsL : idsR;
    const float* dis = y ? disL : disR;
    __hip_bfloat16* hs = y ? hsL : hsR;
    __shared__ float sW[D][D];
    __shared__ float sx[16][D + 1];
    int t = threadIdx.x;
    int j = t & 15, g = t >> 4;
    sW[g][j] = W[t];
    int i = (blockIdx.x << 4) + g;
    sx[g][j] = emb[(size_t)ids[i] * D + j];
    __syncthreads();
    float acc = 0.f;
#pragma unroll
    for (int k = 0; k < D; k++) acc += sx[g][k] * sW[k][j];
    hs[(size_t)i * D + j] = __float2bfloat16(acc * dis[i]);
}

// ---- G1: entry-driven gather (8 lanes per edge, 1 segment/edge), LDS float
//      accumulation, per-node epilogue: self + bias + relu + W2 -> hs2 ----
__global__ __launch_bounds__(256) void g1_kernel(
        const unsigned int* __restrict__ slabR, const unsigned int* __restrict__ slabL,
        const int* __restrict__ gcurR, const int* __restrict__ gcurL,
        const __hip_bfloat16* __restrict__ hs1R, const __hip_bfloat16* __restrict__ hs1L,
        const float* __restrict__ disR, const float* __restrict__ disL,
        const float* __restrict__ b1, const float* __restrict__ W2,
        __hip_bfloat16* __restrict__ hs2R, __hip_bfloat16* __restrict__ hs2L) {
    int y = blockIdx.y;
    const unsigned int* slab = y ? slabL : slabR;
    const int* gcur = y ? gcurL : gcurR;
    const __hip_bfloat16* hs1 = y ? hs1L : hs1R;
    const float* dis = y ? disL : disR;
    __hip_bfloat16* hs2 = y ? hs2L : hs2R;

    __shared__ float acc[BNODES][D + 1];
    __shared__ float sW[D][D];
    int t = threadIdx.x;
    sW[t >> 4][t & 15] = W2[t];
    for (int idx = t; idx < BNODES * (D + 1); idx += 256)
        ((float*)acc)[idx] = 0.f;
    int b = blockIdx.x;
    int cnt = gcur[b]; if (cnt > CAP) cnt = CAP;
    const unsigned int* sl = slab + (size_t)b * CAP;
    __syncthreads();

    int jp = t & 7, eg = t >> 3;          // 32 edges processed per block step
    int ei = eg;
    for (; ei + 96 < cnt; ei += 128) {
        unsigned int r0 = __builtin_nontemporal_load(sl + ei);
        unsigned int r1 = __builtin_nontemporal_load(sl + ei + 32);
        unsigned int r2 = __builtin_nontemporal_load(sl + ei + 64);
        unsigned int r3 = __builtin_nontemporal_load(sl + ei + 96);
        float2 f0 = __bfloat1622float2(*(const __hip_bfloat162*)(hs1 + (size_t)(r0 & 0x3FFFFu) * D + 2 * jp));
        float2 f1 = __bfloat1622float2(*(const __hip_bfloat162*)(hs1 + (size_t)(r1 & 0x3FFFFu) * D + 2 * jp));
        float2 f2 = __bfloat1622float2(*(const __hip_bfloat162*)(hs1 + (size_t)(r2 & 0x3FFFFu) * D + 2 * jp));
        float2 f3 = __bfloat1622float2(*(const __hip_bfloat162*)(hs1 + (size_t)(r3 & 0x3FFFFu) * D + 2 * jp));
        atomicAdd(&acc[r0 >> 18][2 * jp], f0.x);
        atomicAdd(&acc[r0 >> 18][2 * jp + 1], f0.y);
        atomicAdd(&acc[r1 >> 18][2 * jp], f1.x);
        atomicAdd(&acc[r1 >> 18][2 * jp + 1], f1.y);
        atomicAdd(&acc[r2 >> 18][2 * jp], f2.x);
        atomicAdd(&acc[r2 >> 18][2 * jp + 1], f2.y);
        atomicAdd(&acc[r3 >> 18][2 * jp], f3.x);
        atomicAdd(&acc[r3 >> 18][2 * jp + 1], f3.y);
    }
    for (; ei < cnt; ei += 32) {
        unsigned int r0 = __builtin_nontemporal_load(sl + ei);
        float2 f0 = __bfloat1622float2(*(const __hip_bfloat162*)(hs1 + (size_t)(r0 & 0x3FFFFu) * D + 2 * jp));
        atomicAdd(&acc[r0 >> 18][2 * jp], f0.x);
        atomicAdd(&acc[r0 >> 18][2 * jp + 1], f0.y);
    }
    __syncthreads();

    int node = (b << 8) + t;
    if (node < N_NODES) {
        float di = dis[node];
        const uint4* hrow = (const uint4*)(hs1 + (size_t)node * D);
        uint4 s0 = hrow[0], s1 = hrow[1];
        float xv[D];
        const __hip_bfloat162* p0 = (const __hip_bfloat162*)&s0;
        const __hip_bfloat162* p1 = (const __hip_bfloat162*)&s1;
#pragma unroll
        for (int q = 0; q < 4; q++) {
            float2 f = __bfloat1622float2(p0[q]);
            xv[2 * q] = f.x; xv[2 * q + 1] = f.y;
            float2 g = __bfloat1622float2(p1[q]);
            xv[8 + 2 * q] = g.x; xv[8 + 2 * q + 1] = g.y;
        }
#pragma unroll
        for (int f = 0; f < D; f++)
            xv[f] = fmaxf((acc[t][f] + xv[f]) * di + b1[f], 0.f);
        uint4 o0, o1;
        __hip_bfloat162* q0 = (__hip_bfloat162*)&o0;
        __hip_bfloat162* q1 = (__hip_bfloat162*)&o1;
#pragma unroll
        for (int j = 0; j < D; j += 2) {
            float a0 = 0.f, a1 = 0.f;
#pragma unroll
            for (int k = 0; k < D; k++) {
                a0 += xv[k] * sW[k][j];
                a1 += xv[k] * sW[k][j + 1];
            }
            __hip_bfloat162 pk = __float22bfloat162_rn(make_float2(a0 * di, a1 * di));
            if (j < 8) q0[j >> 1] = pk; else q1[(j - 8) >> 1] = pk;
        }
        uint4* orow = (uint4*)(hs2 + (size_t)node * D);
        orow[0] = o0; orow[1] = o1;
    }
}

// ---- G2: entry-driven gather layer2 + fused mean-pool partial reduction ----
__global__ __launch_bounds__(256) void g2_kernel(
        const unsigned int* __restrict__ slabR, const unsigned int* __restrict__ slabL,
        const int* __restrict__ gcurR, const int* __restrict__ gcurL,
        const __hip_bfloat16* __restrict__ hs2R, const __hip_bfloat16* __restrict__ hs2L,
        const float* __restrict__ disR, const float* __restrict__ disL,
        const float* __restrict__ b2,
        const int* __restrict__ batR, const int* __restrict__ batL,
        float* __restrict__ sumsR, float* __restrict__ sumsL,
        float* __restrict__ cntR, float* __restrict__ cntL) {
    int y = blockIdx.y;
    const unsigned int* slab = y ? slabL : slabR;
    const int* gcur = y ? gcurL : gcurR;
    const __hip_bfloat16* hs2 = y ? hs2L : hs2R;
    const float* dis = y ? disL : disR;
    const int* batch = y ? batL : batR;
    float* sums = y ? sumsL : sumsR;
    float* cnt = y ? cntL : cntR;

    __shared__ float acc[BNODES][D + 1];
    __shared__ float gacc[16][D + 1];
    __shared__ int gcnt[16];
    int t = threadIdx.x;
    for (int idx = t; idx < BNODES * (D + 1); idx += 256)
        ((float*)acc)[idx] = 0.f;
    for (int idx = t; idx < 16 * (D + 1); idx += 256)
        ((float*)gacc)[idx] = 0.f;
    if (t < 16) gcnt[t] = 0;
    int b = blockIdx.x;
    int ec = gcur[b]; if (ec > CAP) ec = CAP;
    const unsigned int* sl = slab + (size_t)b * CAP;
    __syncthreads();

    int jp = t & 7, eg = t >> 3;
    int ei = eg;
    for (; ei + 96 < ec; ei += 128) {
        unsigned int r0 = __builtin_nontemporal_load(sl + ei);
        unsigned int r1 = __builtin_nontemporal_load(sl + ei + 32);
        unsigned int r2 = __builtin_nontemporal_load(sl + ei + 64);
        unsigned int r3 = __builtin_nontemporal_load(sl + ei + 96);
        float2 f0 = __bfloat1622float2(*(const __hip_bfloat162*)(hs2 + (size_t)(r0 & 0x3FFFFu) * D + 2 * jp));
        float2 f1 = __bfloat1622float2(*(const __hip_bfloat162*)(hs2 + (size_t)(r1 & 0x3FFFFu) * D + 2 * jp));
        float2 f2 = __bfloat1622float2(*(const __hip_bfloat162*)(hs2 + (size_t)(r2 & 0x3FFFFu) * D + 2 * jp));
        float2 f3 = __bfloat1622float2(*(const __hip_bfloat162*)(hs2 + (size_t)(r3 & 0x3FFFFu) * D + 2 * jp));
        atomicAdd(&acc[r0 >> 18][2 * jp], f0.x);
        atomicAdd(&acc[r0 >> 18][2 * jp + 1], f0.y);
        atomicAdd(&acc[r1 >> 18][2 * jp], f1.x);
        atomicAdd(&acc[r1 >> 18][2 * jp + 1], f1.y);
        atomicAdd(&acc[r2 >> 18][2 * jp], f2.x);
        atomicAdd(&acc[r2 >> 18][2 * jp + 1], f2.y);
        atomicAdd(&acc[r3 >> 18][2 * jp], f3.x);
        atomicAdd(&acc[r3 >> 18][2 * jp + 1], f3.y);
    }
    for (; ei < ec; ei += 32) {
        unsigned int r0 = __builtin_nontemporal_load(sl + ei);
        float2 f0 = __bfloat1622float2(*(const __hip_bfloat162*)(hs2 + (size_t)(r0 & 0x3FFFFu) * D + 2 * jp));
        atomicAdd(&acc[r0 >> 18][2 * jp], f0.x);
        atomicAdd(&acc[r0 >> 18][2 * jp + 1], f0.y);
    }
    __syncthreads();

    int b0 = batch[b << 8];
    int node = (b << 8) + t;
    if (node < N_NODES) {
        float di = dis[node];
        const uint4* hrow = (const uint4*)(hs2 + (size_t)node * D);
        uint4 s0 = hrow[0], s1 = hrow[1];
        float vv[D];
        const __hip_bfloat162* p0 = (const __hip_bfloat162*)&s0;
        const __hip_bfloat162* p1 = (const __hip_bfloat162*)&s1;
#pragma unroll
        for (int q = 0; q < 4; q++) {
            float2 f = __bfloat1622float2(p0[q]);
            vv[2 * q] = f.x; vv[2 * q + 1] = f.y;
            float2 g = __bfloat1622float2(p1[q]);
            vv[8 + 2 * q] = g.x; vv[8 + 2 * q + 1] = g.y;
        }
#pragma unroll
        for (int f = 0; f < D; f++)
            vv[f] = (acc[t][f] + vv[f]) * di + b2[f];
        int bi = batch[node];
        int slot = bi - b0;
        if (slot < 16) {
#pragma unroll
            for (int f = 0; f < D; f++) atomicAdd(&gacc[slot][f], vv[f]);
            atomicAdd(&gcnt[slot], 1);
        } else {
#pragma unroll
            for (int f = 0; f < D; f++) atomicAdd(&sums[(size_t)bi * D + f], vv[f]);
            atomicAdd(&cnt[bi], 1.0f);
        }
    }
    __syncthreads();
    int s = t >> 4, f = t & 15;
    int c = gcnt[s];
    if (c > 0) {
        atomicAdd(&sums[(size_t)(b0 + s) * D + f], gacc[s][f]);
        if (f == 0) atomicAdd(&cnt[b0 + s], (float)c);
    }
}

// ---- final FC ----
__global__ void final_kernel(const float* __restrict__ rs, const float* __restrict__ rc,
                             const float* __restrict__ ls, const float* __restrict__ lc,
                             const float* __restrict__ fcW, const float* __restrict__ fcb,
                             float* __restrict__ out) {
    int b = blockIdx.x * blockDim.x + threadIdx.x;
    if (b >= N_GRAPHS) return;
    float hc[2 * D];
    float rn = fmaxf(rc[b], 1.f), ln = fmaxf(lc[b], 1.f);
#pragma unroll
    for (int j = 0; j < D; j++) {
        hc[j]     = rs[b * D + j] / rn;
        hc[D + j] = ls[b * D + j] / ln;
    }
#pragma unroll
    for (int c = 0; c < 6; c++) {
        float acc = fcb[c];
#pragma unroll
        for (int j = 0; j < 2 * D; j++) acc += hc[j] * fcW[c * 2 * D + j];
        if (c < 3) out[b * 3 + c] = acc;
        else       out[N_GRAPHS * 3 + b * 3 + (c - 3)] = acc;
    }
}

extern "C" void kernel_launch(void* const* d_in, const int* in_sizes, int n_in,
                              void* d_out, int out_size, void* d_ws, size_t ws_size,
                              hipStream_t stream) {
    const float* emb = (const float*)d_in[0];
    const float* W1  = (const float*)d_in[1];
    const float* b1  = (const float*)d_in[2];
    const float* W2  = (const float*)d_in[3];
    const float* b2  = (const float*)d_in[4];
    const float* fcW = (const float*)d_in[5];
    const float* fcb = (const float*)d_in[6];
    const int* rx = (const int*)d_in[7];
    const int* re = (const int*)d_in[8];
    const int* rb = (const int*)d_in[9];
    const int* lx = (const int*)d_in[10];
    const int* le = (const int*)d_in[11];
    const int* lb = (const int*)d_in[12];
    float* out = (float*)d_out;

    char* w = (char*)d_ws;
    unsigned int* slabR = (unsigned int*)w;    w += (size_t)NBUK * CAP * 4;
    unsigned int* slabL = (unsigned int*)w;    w += (size_t)NBUK * CAP * 4;
    __hip_bfloat16* hs1R = (__hip_bfloat16*)w; w += (size_t)N_NODES * D * 2;
    __hip_bfloat16* hs1L = (__hip_bfloat16*)w; w += (size_t)N_NODES * D * 2;
    __hip_bfloat16* hs2R = (__hip_bfloat16*)w; w += (size_t)N_NODES * D * 2;
    __hip_bfloat16* hs2L = (__hip_bfloat16*)w; w += (size_t)N_NODES * D * 2;
    float* disR = (float*)w;                   w += (size_t)N_NODES * 4;
    float* disL = (float*)w;                   w += (size_t)N_NODES * 4;
    // zero-init region: gcurR, gcurL, sums0, cnt0, sums1, cnt1 (single memset)
    char* zbase = w;
    int* gcurR = (int*)w;                      w += (size_t)NBUK * 4;
    int* gcurL = (int*)w;                      w += (size_t)NBUK * 4;
    float* sums0 = (float*)w;                  w += (size_t)N_GRAPHS * D * 4;
    float* cnt0  = (float*)w;                  w += (size_t)N_GRAPHS * 4;
    float* sums1 = (float*)w;                  w += (size_t)N_GRAPHS * D * 4;
    float* cnt1  = (float*)w;                  w += (size_t)N_GRAPHS * 4;
    size_t zsize = (size_t)(w - zbase);

    const int* srcR = re;  const int* dstR = re + NEDGE;
    const int* srcL = le;  const int* dstL = le + NEDGE;

    hipMemsetAsync(zbase, 0, zsize, stream);

    // ---- CSR build: single sort pass, bucket-grouped (unsorted within bucket) ----
    pA<<<dim3(NCH, 2), 1024, 0, stream>>>(srcR, dstR, srcL, dstL,
                                          slabR, slabL, gcurR, gcurL);
    pD<<<dim3(NBUK, 2), 256, 0, stream>>>(slabR, slabL, gcurR, gcurL, disR, disL);

    // ---- fused GCN pipeline ----
    t1_kernel<<<dim3(GBLK, 2), 256, 0, stream>>>(rx, lx, emb, W1, disR, disL, hs1R, hs1L);
    g1_kernel<<<dim3(NBUK, 2), 256, 0, stream>>>(slabR, slabL, gcurR, gcurL,
                                                 hs1R, hs1L, disR, disL, b1, W2,
                                                 hs2R, hs2L);
    g2_kernel<<<dim3(NBUK, 2), 256, 0, stream>>>(slabR, slabL, gcurR, gcurL,
                                                 hs2R, hs2L, disR, disL, b2, rb, lb,
                                                 sums0, sums1, cnt0, cnt1);
    final_kernel<<<(N_GRAPHS + 255) / 256, 256, 0, stream>>>(
        sums0, cnt0, sums1, cnt1, fcW, fcb, out);
}

// Round 3
// 540.702 us; speedup vs baseline: 4.8442x; 4.8442x over previous
//
#include <hip/hip_runtime.h>
#include <hip/hip_bf16.h>

#define N_NODES 200000
#define N_GRAPHS 1024
#define D 16
#define NEDGE 6400000

#define BNODES 256                 // nodes per bucket: bucket = dst >> 8
#define NBUK 782                   // ceil(200000/256)
#define NCH 512                    // edge chunks
#define ECHUNK 12500               // NEDGE / NCH (exact)
#define OSTRIDE (NBUK + 1)         // 783
#define CAP 9216                   // bucket slab capacity (mean 8192, sd ~90 -> 11 sigma)
#define GBLK 12500                 // t1 blocks: 16 nodes x 16 lanes
#define GHALF 6250                 // gather blocks per protein: 32 nodes x 8 lanes

// ---- pA (fused R+L): sort one 12500-edge chunk by bucket in LDS, coalesced writeback ----
__global__ __launch_bounds__(1024) void pA(
        const int* __restrict__ srcR, const int* __restrict__ dstR,
        const int* __restrict__ srcL, const int* __restrict__ dstL,
        unsigned int* __restrict__ slabC_R, unsigned int* __restrict__ slabC_L,
        int* __restrict__ offsT_R, int* __restrict__ offsT_L) {
    const int* src = blockIdx.y ? srcL : srcR;
    const int* dst = blockIdx.y ? dstL : dstR;
    unsigned int* slabC = blockIdx.y ? slabC_L : slabC_R;
    int* offsT = blockIdx.y ? offsT_L : offsT_R;

    __shared__ unsigned int stage[ECHUNK];   // 50 KB
    __shared__ int lh[NBUK];
    __shared__ int lcur[NBUK];
    __shared__ int wsum[16];
    int t = threadIdx.x;
    int wave = t >> 6, lane = t & 63;
    int c = blockIdx.x;
    int base = c * ECHUNK;

    for (int k = t; k < NBUK; k += 1024) lh[k] = 0;
    __syncthreads();
    for (int e = t; e < ECHUNK; e += 1024)
        atomicAdd(&lh[((unsigned int)dst[base + e]) >> 8], 1);
    __syncthreads();

    int v = (t < NBUK) ? lh[t] : 0;
    int x = v;
#pragma unroll
    for (int d0 = 1; d0 < 64; d0 <<= 1) {
        int y = __shfl_up(x, d0, 64);
        if (lane >= d0) x += y;
    }
    if (lane == 63) wsum[wave] = x;
    __syncthreads();
    if (wave == 0 && lane < 16) {
        int s = wsum[lane];
#pragma unroll
        for (int d0 = 1; d0 < 16; d0 <<= 1) {
            int y = __shfl_up(s, d0, 64);
            if (lane >= d0) s += y;
        }
        wsum[lane] = s;
    }
    __syncthreads();
    int excl = x - v + (wave ? wsum[wave - 1] : 0);
    if (t < NBUK) lcur[t] = excl;
    __syncthreads();

    for (int e = t; e < ECHUNK; e += 1024) {
        int d = dst[base + e];
        int s = src[base + e];
        int pos = atomicAdd(&lcur[d >> 8], 1);
        stage[pos] = ((unsigned int)(d & 255) << 18) | (unsigned int)s;
    }
    __syncthreads();
    for (int e = t; e < ECHUNK; e += 1024) slabC[base + e] = stage[e];
    if (t < NBUK) offsT[c * OSTRIDE + t] = excl;
    if (t == 0) offsT[c * OSTRIDE + NBUK] = ECHUNK;
}

// ---- transpose offsT [NCH][OSTRIDE] -> offsTT [OSTRIDE][NCH] ----
__global__ __launch_bounds__(256) void tr_kernel(
        const int* __restrict__ offsT_R, const int* __restrict__ offsT_L,
        int* __restrict__ offsTT_R, int* __restrict__ offsTT_L) {
    const int* in = blockIdx.z ? offsT_L : offsT_R;
    int* outp = blockIdx.z ? offsTT_L : offsTT_R;
    __shared__ int tile[32][33];
    int lx = threadIdx.x & 31, ly = threadIdx.x >> 5;   // 32 x 8
#pragma unroll
    for (int r = 0; r < 32; r += 8) {
        int row = blockIdx.y * 32 + ly + r;             // chunk index (<512 exact)
        int col = blockIdx.x * 32 + lx;                 // OSTRIDE index
        if (col < OSTRIDE) tile[ly + r][lx] = in[row * OSTRIDE + col];
    }
    __syncthreads();
#pragma unroll
    for (int r = 0; r < 32; r += 8) {
        int orow = blockIdx.x * 32 + ly + r;            // OSTRIDE index
        int ocol = blockIdx.y * 32 + lx;                // chunk index
        if (orow < OSTRIDE) outp[orow * NCH + ocol] = tile[lx][ly + r];
    }
}

// ---- pB (fused R+L): single-pass per-bucket counting sort (LDS-staged input) ----
__global__ __launch_bounds__(256) void pB(
        const unsigned int* __restrict__ slabC_R, const unsigned int* __restrict__ slabC_L,
        const int* __restrict__ offsTT_R, const int* __restrict__ offsTT_L,
        unsigned int* __restrict__ slabR, unsigned int* __restrict__ slabL,
        int2* __restrict__ metaR, int2* __restrict__ metaL,
        float* __restrict__ disR, float* __restrict__ disL) {
    int y = blockIdx.y;
    const unsigned int* slabC = y ? slabC_L : slabC_R;
    const int* offsTT = y ? offsTT_L : offsTT_R;
    unsigned int* slab = y ? slabL : slabR;
    int2* meta = y ? metaL : metaR;
    float* dis = y ? disL : disR;

    __shared__ unsigned int sin_[CAP];       // 36.9 KB
    __shared__ unsigned int sout[CAP];       // 36.9 KB
    __shared__ int hcnt[BNODES], hoff[BNODES], hcur[BNODES];
    __shared__ int wtot[4];
    __shared__ int totc;
    int t = threadIdx.x;
    int lane = t & 63, wave = t >> 6;
    int b = blockIdx.x;

    // run bounds for this thread's two chunks (coalesced row reads of offsTT)
    int a0 = offsTT[b * NCH + t],        e0 = offsTT[(b + 1) * NCH + t];
    int a1 = offsTT[b * NCH + t + 256],  e1 = offsTT[(b + 1) * NCH + t + 256];
    int len = (e0 - a0) + (e1 - a1);

    // block exclusive scan of len -> sbase
    int x = len;
#pragma unroll
    for (int d0 = 1; d0 < 64; d0 <<= 1) {
        int yy = __shfl_up(x, d0, 64);
        if (lane >= d0) x += yy;
    }
    if (lane == 63) wtot[wave] = x;
    hcnt[t] = 0;
    __syncthreads();
    int pre = 0;
    for (int w2 = 0; w2 < wave; w2++) pre += wtot[w2];
    int sbase = x - len + pre;
    if (t == 255) totc = sbase + len;
    __syncthreads();

    // stage both runs into sin_ (vectorized uint4 reads)
    int p = sbase;
    {
        int cb = t * ECHUNK;
        for (int i = (a0 & ~3); i < e0; i += 4) {
            uint4 v = *(const uint4*)(slabC + cb + i);
            unsigned int vv[4] = {v.x, v.y, v.z, v.w};
#pragma unroll
            for (int k = 0; k < 4; k++) {
                int idx = i + k;
                if (idx >= a0 && idx < e0) { if (p < CAP) sin_[p] = vv[k]; p++; }
            }
        }
        cb = (t + 256) * ECHUNK;
        for (int i = (a1 & ~3); i < e1; i += 4) {
            uint4 v = *(const uint4*)(slabC + cb + i);
            unsigned int vv[4] = {v.x, v.y, v.z, v.w};
#pragma unroll
            for (int k = 0; k < 4; k++) {
                int idx = i + k;
                if (idx >= a1 && idx < e1) { if (p < CAP) sin_[p] = vv[k]; p++; }
            }
        }
    }
    __syncthreads();
    int cnt = totc;
    if (cnt > CAP) cnt = CAP;   // statistically unreachable

    // count
    for (int i = t; i < cnt; i += 256) atomicAdd(&hcnt[sin_[i] >> 18], 1);
    __syncthreads();

    // exclusive scan of hcnt
    int v2 = hcnt[t];
    int x2 = v2;
#pragma unroll
    for (int d0 = 1; d0 < 64; d0 <<= 1) {
        int yy = __shfl_up(x2, d0, 64);
        if (lane >= d0) x2 += yy;
    }
    if (lane == 63) wtot[wave] = x2;
    __syncthreads();
    int pre2 = 0;
    for (int w2 = 0; w2 < wave; w2++) pre2 += wtot[w2];
    int ex = x2 - v2 + pre2;
    hoff[t] = ex;
    hcur[t] = ex;
    __syncthreads();

    // place
    for (int i = t; i < cnt; i += 256) {
        unsigned int r = sin_[i];
        int pp = atomicAdd(&hcur[r >> 18], 1);
        if (pp < CAP) sout[pp] = r & 0x3FFFFu;
    }
    __syncthreads();

    int gb = b * CAP;
    for (int i = t; i < cnt; i += 256) slab[gb + i] = sout[i];   // coalesced
    int node = (b << 8) + t;
    if (node < N_NODES) {
        meta[node] = make_int2(gb + hoff[t], gb + hoff[t] + hcnt[t]);
        dis[node] = rsqrtf((float)hcnt[t] + 1.0f);
    }
}

// ---- t1 (fused R+L): hs1[i,j] = bf16( (emb[ids[i]] @ W1)[j] * dis[i] ) ----
__global__ __launch_bounds__(256) void t1_kernel(
        const int* __restrict__ idsR, const int* __restrict__ idsL,
        const float* __restrict__ emb, const float* __restrict__ W,
        const float* __restrict__ disR, const float* __restrict__ disL,
        __hip_bfloat16* __restrict__ hsR, __hip_bfloat16* __restrict__ hsL) {
    int y = blockIdx.y;
    const int* ids = y ? idsL : idsR;
    const float* dis = y ? disL : disR;
    __hip_bfloat16* hs = y ? hsL : hsR;
    __shared__ float sW[D][D];
    __shared__ float sx[16][D + 1];
    int t = threadIdx.x;
    int j = t & 15, g = t >> 4;
    sW[g][j] = W[t];
    int i = (blockIdx.x << 4) + g;
    sx[g][j] = emb[(size_t)ids[i] * D + j];
    __syncthreads();
    float acc = 0.f;
#pragma unroll
    for (int k = 0; k < D; k++) acc += sx[g][k] * sW[k][j];
    hs[(size_t)i * D + j] = __float2bfloat16(acc * dis[i]);
}

// ---- G1: gather layer1 + relu + transform2 -> hs2. 32 nodes/block, 8 lanes/node.
//      16-edge register batches: 2 csr words + 16 in-flight gathers per wave
//      (attacks the latency*MLP wall; round-0 VGPR=24 held only ~8 in flight) ----
__global__ __launch_bounds__(256) void g1_kernel(
        const int2* __restrict__ metaR, const int2* __restrict__ metaL,
        const unsigned int* __restrict__ csrR, const unsigned int* __restrict__ csrL,
        const __hip_bfloat16* __restrict__ hs1R, const __hip_bfloat16* __restrict__ hs1L,
        const float* __restrict__ disR, const float* __restrict__ disL,
        const float* __restrict__ b1, const float* __restrict__ W2,
        __hip_bfloat16* __restrict__ hs2R, __hip_bfloat16* __restrict__ hs2L) {
    int half = (blockIdx.x >= GHALF);
    int bx = blockIdx.x - (half ? GHALF : 0);
    const int2* meta = half ? metaL : metaR;
    const unsigned int* csr = half ? csrL : csrR;
    const __hip_bfloat16* hs1 = half ? hs1L : hs1R;
    const float* dis = half ? disL : disR;
    __hip_bfloat16* hs2 = half ? hs2L : hs2R;

    __shared__ float sW[D][D];
    __shared__ float sx[32][D + 1];
    int t = threadIdx.x;
    int jp = t & 7, g = t >> 3;
    sW[t >> 4][t & 15] = W2[t];
    int i = (bx << 5) + g;
    int2 be = meta[i];
    float2 acc = __bfloat1622float2(
        *(const __hip_bfloat162*)(hs1 + (size_t)i * D + 2 * jp));
    int e = be.x, end = be.y;
    // 16-deep batches: issue all 16 gathers before consuming
    for (; e + 16 <= end; e += 16) {
        int m0 = (int)__builtin_nontemporal_load(csr + e + jp);
        int m1 = (int)__builtin_nontemporal_load(csr + e + 8 + jp);
        unsigned int u[16];
#pragma unroll
        for (int n = 0; n < 8; n++) {
            int s = __shfl(m0, n, 8);
            u[n] = *(const unsigned int*)(hs1 + (size_t)s * D + 2 * jp);
        }
#pragma unroll
        for (int n = 0; n < 8; n++) {
            int s = __shfl(m1, n, 8);
            u[8 + n] = *(const unsigned int*)(hs1 + (size_t)s * D + 2 * jp);
        }
#pragma unroll
        for (int n = 0; n < 16; n++) {
            float2 f = __bfloat1622float2(*(const __hip_bfloat162*)&u[n]);
            acc.x += f.x; acc.y += f.y;
        }
    }
    for (; e + 8 <= end; e += 8) {
        int my = (int)__builtin_nontemporal_load(csr + e + jp);
        unsigned int u[8];
#pragma unroll
        for (int n = 0; n < 8; n++) {
            int s = __shfl(my, n, 8);
            u[n] = *(const unsigned int*)(hs1 + (size_t)s * D + 2 * jp);
        }
#pragma unroll
        for (int n = 0; n < 8; n++) {
            float2 f = __bfloat1622float2(*(const __hip_bfloat162*)&u[n]);
            acc.x += f.x; acc.y += f.y;
        }
    }
    for (; e < end; e++) {
        int s = (int)csr[e];
        float2 f = __bfloat1622float2(
            *(const __hip_bfloat162*)(hs1 + (size_t)s * D + 2 * jp));
        acc.x += f.x; acc.y += f.y;
    }
    float di = dis[i];
    sx[g][2 * jp]     = fmaxf(acc.x * di + b1[2 * jp], 0.f);
    sx[g][2 * jp + 1] = fmaxf(acc.y * di + b1[2 * jp + 1], 0.f);
    __syncthreads();
    float a0 = 0.f, a1 = 0.f;
#pragma unroll
    for (int k = 0; k < D; k++) {
        float xv = sx[g][k];
        a0 += xv * sW[k][2 * jp];
        a1 += xv * sW[k][2 * jp + 1];
    }
    *(__hip_bfloat162*)(hs2 + (size_t)i * D + 2 * jp) =
        __float22bfloat162_rn(make_float2(a0 * di, a1 * di));
}

// ---- G2: gather layer2 + fused mean-pool partial reduction (16-deep batches) ----
__global__ __launch_bounds__(256) void g2_kernel(
        const int2* __restrict__ metaR, const int2* __restrict__ metaL,
        const unsigned int* __restrict__ csrR, const unsigned int* __restrict__ csrL,
        const __hip_bfloat16* __restrict__ hs2R, const __hip_bfloat16* __restrict__ hs2L,
        const float* __restrict__ disR, const float* __restrict__ disL,
        const float* __restrict__ b2,
        const int* __restrict__ batR, const int* __restrict__ batL,
        float* __restrict__ sumsR, float* __restrict__ sumsL,
        float* __restrict__ cntR, float* __restrict__ cntL) {
    int half = (blockIdx.x >= GHALF);
    int bx = blockIdx.x - (half ? GHALF : 0);
    const int2* meta = half ? metaL : metaR;
    const unsigned int* csr = half ? csrL : csrR;
    const __hip_bfloat16* hs2 = half ? hs2L : hs2R;
    const float* dis = half ? disL : disR;
    const int* batch = half ? batL : batR;
    float* sums = half ? sumsL : sumsR;
    float* cnt = half ? cntL : cntR;

    __shared__ float sv[32][D + 1];
    __shared__ int sb[32];
    int t = threadIdx.x;
    int jp = t & 7, g = t >> 3;
    int i = (bx << 5) + g;
    int2 be = meta[i];
    float2 acc = __bfloat1622float2(
        *(const __hip_bfloat162*)(hs2 + (size_t)i * D + 2 * jp));
    int e = be.x, end = be.y;
    for (; e + 16 <= end; e += 16) {
        int m0 = (int)__builtin_nontemporal_load(csr + e + jp);
        int m1 = (int)__builtin_nontemporal_load(csr + e + 8 + jp);
        unsigned int u[16];
#pragma unroll
        for (int n = 0; n < 8; n++) {
            int s = __shfl(m0, n, 8);
            u[n] = *(const unsigned int*)(hs2 + (size_t)s * D + 2 * jp);
        }
#pragma unroll
        for (int n = 0; n < 8; n++) {
            int s = __shfl(m1, n, 8);
            u[8 + n] = *(const unsigned int*)(hs2 + (size_t)s * D + 2 * jp);
        }
#pragma unroll
        for (int n = 0; n < 16; n++) {
            float2 f = __bfloat1622float2(*(const __hip_bfloat162*)&u[n]);
            acc.x += f.x; acc.y += f.y;
        }
    }
    for (; e + 8 <= end; e += 8) {
        int my = (int)__builtin_nontemporal_load(csr + e + jp);
        unsigned int u[8];
#pragma unroll
        for (int n = 0; n < 8; n++) {
            int s = __shfl(my, n, 8);
            u[n] = *(const unsigned int*)(hs2 + (size_t)s * D + 2 * jp);
        }
#pragma unroll
        for (int n = 0; n < 8; n++) {
            float2 f = __bfloat1622float2(*(const __hip_bfloat162*)&u[n]);
            acc.x += f.x; acc.y += f.y;
        }
    }
    for (; e < end; e++) {
        int s = (int)csr[e];
        float2 f = __bfloat1622float2(
            *(const __hip_bfloat162*)(hs2 + (size_t)s * D + 2 * jp));
        acc.x += f.x; acc.y += f.y;
    }
    float di = dis[i];
    int bi = batch[i];
    sv[g][2 * jp]     = acc.x * di + b2[2 * jp];
    sv[g][2 * jp + 1] = acc.y * di + b2[2 * jp + 1];
    if (jp == 0) sb[g] = bi;
    __syncthreads();
    bool runend = (g == 31) || (sb[g + 1] != bi);
    if (runend) {
        float s0 = 0.f, s1 = 0.f;
        int gg = g;
        while (gg >= 0 && sb[gg] == bi) { s0 += sv[gg][2 * jp]; s1 += sv[gg][2 * jp + 1]; gg--; }
        atomicAdd(&sums[bi * D + 2 * jp], s0);
        atomicAdd(&sums[bi * D + 2 * jp + 1], s1);
        if (jp == 0) atomicAdd(&cnt[bi], (float)(g - gg));
    }
}

// ---- final FC ----
__global__ void final_kernel(const float* __restrict__ rs, const float* __restrict__ rc,
                             const float* __restrict__ ls, const float* __restrict__ lc,
                             const float* __restrict__ fcW, const float* __restrict__ fcb,
                             float* __restrict__ out) {
    int b = blockIdx.x * blockDim.x + threadIdx.x;
    if (b >= N_GRAPHS) return;
    float hc[2 * D];
    float rn = fmaxf(rc[b], 1.f), ln = fmaxf(lc[b], 1.f);
#pragma unroll
    for (int j = 0; j < D; j++) {
        hc[j]     = rs[b * D + j] / rn;
        hc[D + j] = ls[b * D + j] / ln;
    }
#pragma unroll
    for (int c = 0; c < 6; c++) {
        float acc = fcb[c];
#pragma unroll
        for (int j = 0; j < 2 * D; j++) acc += hc[j] * fcW[c * 2 * D + j];
        if (c < 3) out[b * 3 + c] = acc;
        else       out[N_GRAPHS * 3 + b * 3 + (c - 3)] = acc;
    }
}

extern "C" void kernel_launch(void* const* d_in, const int* in_sizes, int n_in,
                              void* d_out, int out_size, void* d_ws, size_t ws_size,
                              hipStream_t stream) {
    const float* emb = (const float*)d_in[0];
    const float* W1  = (const float*)d_in[1];
    const float* b1  = (const float*)d_in[2];
    const float* W2  = (const float*)d_in[3];
    const float* b2  = (const float*)d_in[4];
    const float* fcW = (const float*)d_in[5];
    const float* fcb = (const float*)d_in[6];
    const int* rx = (const int*)d_in[7];
    const int* re = (const int*)d_in[8];
    const int* rb = (const int*)d_in[9];
    const int* lx = (const int*)d_in[10];
    const int* le = (const int*)d_in[11];
    const int* lb = (const int*)d_in[12];
    float* out = (float*)d_out;

    char* w = (char*)d_ws;
    // slabC region (51.2 MB), dead after pB; bf16 hs arrays (25.6 MB) overlay it.
    unsigned int* slabC_R = (unsigned int*)w;
    __hip_bfloat16* hs1R = (__hip_bfloat16*)w;
    __hip_bfloat16* hs1L = hs1R + (size_t)N_NODES * D;
    __hip_bfloat16* hs2R = hs1L + (size_t)N_NODES * D;
    __hip_bfloat16* hs2L = hs2R + (size_t)N_NODES * D;
    w += (size_t)NEDGE * 4;
    unsigned int* slabC_L = (unsigned int*)w;  w += (size_t)NEDGE * 4;
    unsigned int* slabR = (unsigned int*)w;    w += (size_t)NBUK * CAP * 4;
    unsigned int* slabL = (unsigned int*)w;    w += (size_t)NBUK * CAP * 4;
    int* offsT_R = (int*)w;                    w += (size_t)NCH * OSTRIDE * 4;
    int* offsT_L = (int*)w;                    w += (size_t)NCH * OSTRIDE * 4;
    int* offsTT_R = (int*)w;                   w += (size_t)OSTRIDE * NCH * 4;
    int* offsTT_L = (int*)w;                   w += (size_t)OSTRIDE * NCH * 4;
    int2* metaR = (int2*)w;                    w += (size_t)N_NODES * 8;
    int2* metaL = (int2*)w;                    w += (size_t)N_NODES * 8;
    float* disR = (float*)w;                   w += (size_t)N_NODES * 4;
    float* disL = (float*)w;                   w += (size_t)N_NODES * 4;
    float* sums0 = (float*)w;                  w += (size_t)N_GRAPHS * D * 4;
    float* cnt0  = (float*)w;                  w += (size_t)N_GRAPHS * 4;
    float* sums1 = (float*)w;                  w += (size_t)N_GRAPHS * D * 4;
    float* cnt1  = (float*)w;                  w += (size_t)N_GRAPHS * 4;

    const int* srcR = re;  const int* dstR = re + NEDGE;
    const int* srcL = le;  const int* dstL = le + NEDGE;

    hipMemsetAsync(sums0, 0, ((size_t)N_GRAPHS * (D + 1)) * 2 * sizeof(float), stream);

    // ---- CSR build (R+L fused) ----
    pA<<<dim3(NCH, 2), 1024, 0, stream>>>(srcR, dstR, srcL, dstL,
                                          slabC_R, slabC_L, offsT_R, offsT_L);
    tr_kernel<<<dim3((OSTRIDE + 31) / 32, NCH / 32, 2), 256, 0, stream>>>(
        offsT_R, offsT_L, offsTT_R, offsTT_L);
    pB<<<dim3(NBUK, 2), 256, 0, stream>>>(slabC_R, slabC_L, offsTT_R, offsTT_L,
                                          slabR, slabL, metaR, metaL, disR, disL);

    // ---- fused GCN pipeline ----
    t1_kernel<<<dim3(GBLK, 2), 256, 0, stream>>>(rx, lx, emb, W1, disR, disL, hs1R, hs1L);
    g1_kernel<<<2 * GHALF, 256, 0, stream>>>(metaR, metaL, slabR, slabL,
                                             hs1R, hs1L, disR, disL, b1, W2, hs2R, hs2L);
    g2_kernel<<<2 * GHALF, 256, 0, stream>>>(metaR, metaL, slabR, slabL,
                                             hs2R, hs2L, disR, disL, b2, rb, lb,
                                             sums0, sums1, cnt0, cnt1);
    final_kernel<<<(N_GRAPHS + 255) / 256, 256, 0, stream>>>(
        sums0, cnt0, sums1, cnt1, fcW, fcb, out);
}

// Round 4
// 530.903 us; speedup vs baseline: 4.9336x; 1.0185x over previous
//
#include <hip/hip_runtime.h>
#include <hip/hip_bf16.h>

#define N_NODES 200000
#define N_GRAPHS 1024
#define D 16
#define NEDGE 6400000

#define BNODES 256                 // nodes per bucket: bucket = dst >> 8
#define NBUK 782                   // ceil(200000/256)
#define NCH 640                    // edge chunks
#define ECHUNK 10000               // NEDGE / NCH (exact)
#define CAP 9216                   // bucket slab capacity (mean 8192, sd ~90 -> 11 sigma)
#define GBLK 12500                 // t1 blocks: 16 nodes x 16 lanes
#define GHALF 6250                 // gather blocks per protein: 32 nodes x 8 lanes

// ---- pA (fused R+L): sort one 10000-edge chunk by bucket in LDS, then append each
//      bucket-run directly into the global per-bucket slab (atomic run allocation,
//      coalesced run writes). Output: bucket-grouped, unsorted within bucket. ----
__global__ __launch_bounds__(1024) void pA(
        const int* __restrict__ srcR, const int* __restrict__ dstR,
        const int* __restrict__ srcL, const int* __restrict__ dstL,
        unsigned int* __restrict__ slabR, unsigned int* __restrict__ slabL,
        int* __restrict__ gcurR, int* __restrict__ gcurL) {
    const int* src = blockIdx.y ? srcL : srcR;
    const int* dst = blockIdx.y ? dstL : dstR;
    unsigned int* slab = blockIdx.y ? slabL : slabR;
    int* gcur = blockIdx.y ? gcurL : gcurR;

    __shared__ unsigned int stage[ECHUNK];      // 40 KB
    __shared__ unsigned short stageB[ECHUNK];   // 20 KB (bucket id per staged entry)
    __shared__ int lh[NBUK];                    // counts -> append offset (gb - excl)
    __shared__ int lcur[NBUK];
    __shared__ int wsum[16];
    int t = threadIdx.x;
    int wave = t >> 6, lane = t & 63;
    int base = blockIdx.x * ECHUNK;

    for (int k = t; k < NBUK; k += 1024) lh[k] = 0;
    __syncthreads();
    for (int e = t; e < ECHUNK; e += 1024)
        atomicAdd(&lh[((unsigned int)dst[base + e]) >> 8], 1);
    __syncthreads();

    int v = (t < NBUK) ? lh[t] : 0;
    int x = v;
#pragma unroll
    for (int d0 = 1; d0 < 64; d0 <<= 1) {
        int y = __shfl_up(x, d0, 64);
        if (lane >= d0) x += y;
    }
    if (lane == 63) wsum[wave] = x;
    __syncthreads();
    if (wave == 0 && lane < 16) {
        int s = wsum[lane];
#pragma unroll
        for (int d0 = 1; d0 < 16; d0 <<= 1) {
            int y = __shfl_up(s, d0, 64);
            if (lane >= d0) s += y;
        }
        wsum[lane] = s;
    }
    __syncthreads();
    int excl = x - v + (wave ? wsum[wave - 1] : 0);
    if (t < NBUK) lcur[t] = excl;
    __syncthreads();
    // allocate this chunk's run in each bucket's global slab region
    if (t < NBUK) {
        int gb = v ? atomicAdd(&gcur[t], v) : 0;
        lh[t] = gb - excl;                      // global offset = lh[buk] + staged_pos
    }
    __syncthreads();

    for (int e = t; e < ECHUNK; e += 1024) {
        int d = dst[base + e];
        int s = src[base + e];
        int buk = ((unsigned int)d) >> 8;
        int pos = atomicAdd(&lcur[buk], 1);
        stage[pos] = ((unsigned int)(d & 255) << 18) | (unsigned int)s;
        stageB[pos] = (unsigned short)buk;
    }
    __syncthreads();
    for (int e = t; e < ECHUNK; e += 1024) {
        int k = stageB[e];
        int off = lh[k] + e;                    // gb + (e - excl[k])
        slab[(size_t)k * CAP + off] = stage[e];
    }
}

// ---- pB2: in-place per-bucket counting sort from a CONTIGUOUS (coalesced) read.
//      Replaces round-0's offsT/tr/offsTT + scattered-run staging. ----
__global__ __launch_bounds__(256) void pB2(
        unsigned int* __restrict__ slabR, unsigned int* __restrict__ slabL,
        const int* __restrict__ gcurR, const int* __restrict__ gcurL,
        int2* __restrict__ metaR, int2* __restrict__ metaL,
        float* __restrict__ disR, float* __restrict__ disL) {
    int y = blockIdx.y;
    unsigned int* slab = y ? slabL : slabR;
    const int* gcur = y ? gcurL : gcurR;
    int2* meta = y ? metaL : metaR;
    float* dis = y ? disL : disR;

    __shared__ unsigned int sin_[CAP];       // 36.9 KB
    __shared__ unsigned int sout[CAP];       // 36.9 KB
    __shared__ int hcnt[BNODES], hoff[BNODES], hcur[BNODES];
    __shared__ int wtot[4];
    int t = threadIdx.x;
    int lane = t & 63, wave = t >> 6;
    int b = blockIdx.x;
    int cnt = gcur[b]; if (cnt > CAP) cnt = CAP;   // statistically unreachable
    unsigned int* sl = slab + (size_t)b * CAP;
    hcnt[t] = 0;
    __syncthreads();

    // coalesced uint4 stage (i%4==0 and i<cnt implies i+3 < CAP, CAP%4==0)
    for (int i = t * 4; i < cnt; i += 1024) {
        uint4 v = *(const uint4*)(sl + i);
        sin_[i] = v.x; sin_[i + 1] = v.y; sin_[i + 2] = v.z; sin_[i + 3] = v.w;
    }
    __syncthreads();

    // count
    for (int i = t; i < cnt; i += 256) atomicAdd(&hcnt[sin_[i] >> 18], 1);
    __syncthreads();

    // exclusive scan of hcnt
    int v2 = hcnt[t];
    int x2 = v2;
#pragma unroll
    for (int d0 = 1; d0 < 64; d0 <<= 1) {
        int yy = __shfl_up(x2, d0, 64);
        if (lane >= d0) x2 += yy;
    }
    if (lane == 63) wtot[wave] = x2;
    __syncthreads();
    int pre2 = 0;
    for (int w2 = 0; w2 < wave; w2++) pre2 += wtot[w2];
    int ex = x2 - v2 + pre2;
    hoff[t] = ex;
    hcur[t] = ex;
    __syncthreads();

    // place
    for (int i = t; i < cnt; i += 256) {
        unsigned int r = sin_[i];
        int pp = atomicAdd(&hcur[r >> 18], 1);
        sout[pp] = r & 0x3FFFFu;
    }
    __syncthreads();

    // in-place sorted writeback + meta/dis
    int gb = b * CAP;
    for (int i = t; i < cnt; i += 256) sl[i] = sout[i];   // coalesced
    int node = (b << 8) + t;
    if (node < N_NODES) {
        meta[node] = make_int2(gb + hoff[t], gb + hoff[t] + hcnt[t]);
        dis[node] = rsqrtf((float)hcnt[t] + 1.0f);
    }
}

// ---- t1 (fused R+L): hs1[i,j] = bf16( (emb[ids[i]] @ W1)[j] * dis[i] ) ----
__global__ __launch_bounds__(256) void t1_kernel(
        const int* __restrict__ idsR, const int* __restrict__ idsL,
        const float* __restrict__ emb, const float* __restrict__ W,
        const float* __restrict__ disR, const float* __restrict__ disL,
        __hip_bfloat16* __restrict__ hsR, __hip_bfloat16* __restrict__ hsL) {
    int y = blockIdx.y;
    const int* ids = y ? idsL : idsR;
    const float* dis = y ? disL : disR;
    __hip_bfloat16* hs = y ? hsL : hsR;
    __shared__ float sW[D][D];
    __shared__ float sx[16][D + 1];
    int t = threadIdx.x;
    int j = t & 15, g = t >> 4;
    sW[g][j] = W[t];
    int i = (blockIdx.x << 4) + g;
    sx[g][j] = emb[(size_t)ids[i] * D + j];
    __syncthreads();
    float acc = 0.f;
#pragma unroll
    for (int k = 0; k < D; k++) acc += sx[g][k] * sW[k][j];
    hs[(size_t)i * D + j] = __float2bfloat16(acc * dis[i]);
}

// ---- G1: gather layer1 + relu + transform2 -> hs2. 32 nodes/block, 8 lanes/node.
//      grid.x = 2*GHALF; first half = R (temporal L2 separation of the two tables) ----
__global__ __launch_bounds__(256) void g1_kernel(
        const int2* __restrict__ metaR, const int2* __restrict__ metaL,
        const unsigned int* __restrict__ csrR, const unsigned int* __restrict__ csrL,
        const __hip_bfloat16* __restrict__ hs1R, const __hip_bfloat16* __restrict__ hs1L,
        const float* __restrict__ disR, const float* __restrict__ disL,
        const float* __restrict__ b1, const float* __restrict__ W2,
        __hip_bfloat16* __restrict__ hs2R, __hip_bfloat16* __restrict__ hs2L) {
    int half = (blockIdx.x >= GHALF);
    int bx = blockIdx.x - (half ? GHALF : 0);
    const int2* meta = half ? metaL : metaR;
    const unsigned int* csr = half ? csrL : csrR;
    const __hip_bfloat16* hs1 = half ? hs1L : hs1R;
    const float* dis = half ? disL : disR;
    __hip_bfloat16* hs2 = half ? hs2L : hs2R;

    __shared__ float sW[D][D];
    __shared__ float sx[32][D + 1];
    int t = threadIdx.x;
    int jp = t & 7, g = t >> 3;
    sW[t >> 4][t & 15] = W2[t];
    int i = (bx << 5) + g;
    int2 be = meta[i];
    float2 acc = __bfloat1622float2(
        *(const __hip_bfloat162*)(hs1 + (size_t)i * D + 2 * jp));
    int e = be.x, end = be.y;
    for (; e + 8 <= end; e += 8) {
        int my = (int)csr[e + jp];
#pragma unroll
        for (int n = 0; n < 8; n++) {
            int s = __shfl(my, n, 8);
            float2 f = __bfloat1622float2(
                *(const __hip_bfloat162*)(hs1 + (size_t)s * D + 2 * jp));
            acc.x += f.x; acc.y += f.y;
        }
    }
    for (; e < end; e++) {
        int s = csr[e];
        float2 f = __bfloat1622float2(
            *(const __hip_bfloat162*)(hs1 + (size_t)s * D + 2 * jp));
        acc.x += f.x; acc.y += f.y;
    }
    float di = dis[i];
    sx[g][2 * jp]     = fmaxf(acc.x * di + b1[2 * jp], 0.f);
    sx[g][2 * jp + 1] = fmaxf(acc.y * di + b1[2 * jp + 1], 0.f);
    __syncthreads();
    float a0 = 0.f, a1 = 0.f;
#pragma unroll
    for (int k = 0; k < D; k++) {
        float xv = sx[g][k];
        a0 += xv * sW[k][2 * jp];
        a1 += xv * sW[k][2 * jp + 1];
    }
    *(__hip_bfloat162*)(hs2 + (size_t)i * D + 2 * jp) =
        __float22bfloat162_rn(make_float2(a0 * di, a1 * di));
}

// ---- G2: gather layer2 + fused mean-pool partial reduction ----
__global__ __launch_bounds__(256) void g2_kernel(
        const int2* __restrict__ metaR, const int2* __restrict__ metaL,
        const unsigned int* __restrict__ csrR, const unsigned int* __restrict__ csrL,
        const __hip_bfloat16* __restrict__ hs2R, const __hip_bfloat16* __restrict__ hs2L,
        const float* __restrict__ disR, const float* __restrict__ disL,
        const float* __restrict__ b2,
        const int* __restrict__ batR, const int* __restrict__ batL,
        float* __restrict__ sumsR, float* __restrict__ sumsL,
        float* __restrict__ cntR, float* __restrict__ cntL) {
    int half = (blockIdx.x >= GHALF);
    int bx = blockIdx.x - (half ? GHALF : 0);
    const int2* meta = half ? metaL : metaR;
    const unsigned int* csr = half ? csrL : csrR;
    const __hip_bfloat16* hs2 = half ? hs2L : hs2R;
    const float* dis = half ? disL : disR;
    const int* batch = half ? batL : batR;
    float* sums = half ? sumsL : sumsR;
    float* cnt = half ? cntL : cntR;

    __shared__ float sv[32][D + 1];
    __shared__ int sb[32];
    int t = threadIdx.x;
    int jp = t & 7, g = t >> 3;
    int i = (bx << 5) + g;
    int2 be = meta[i];
    float2 acc = __bfloat1622float2(
        *(const __hip_bfloat162*)(hs2 + (size_t)i * D + 2 * jp));
    int e = be.x, end = be.y;
    for (; e + 8 <= end; e += 8) {
        int my = (int)csr[e + jp];
#pragma unroll
        for (int n = 0; n < 8; n++) {
            int s = __shfl(my, n, 8);
            float2 f = __bfloat1622float2(
                *(const __hip_bfloat162*)(hs2 + (size_t)s * D + 2 * jp));
            acc.x += f.x; acc.y += f.y;
        }
    }
    for (; e < end; e++) {
        int s = csr[e];
        float2 f = __bfloat1622float2(
            *(const __hip_bfloat162*)(hs2 + (size_t)s * D + 2 * jp));
        acc.x += f.x; acc.y += f.y;
    }
    float di = dis[i];
    int bi = batch[i];
    sv[g][2 * jp]     = acc.x * di + b2[2 * jp];
    sv[g][2 * jp + 1] = acc.y * di + b2[2 * jp + 1];
    if (jp == 0) sb[g] = bi;
    __syncthreads();
    bool runend = (g == 31) || (sb[g + 1] != bi);
    if (runend) {
        float s0 = 0.f, s1 = 0.f;
        int gg = g;
        while (gg >= 0 && sb[gg] == bi) { s0 += sv[gg][2 * jp]; s1 += sv[gg][2 * jp + 1]; gg--; }
        atomicAdd(&sums[bi * D + 2 * jp], s0);
        atomicAdd(&sums[bi * D + 2 * jp + 1], s1);
        if (jp == 0) atomicAdd(&cnt[bi], (float)(g - gg));
    }
}

// ---- final FC ----
__global__ void final_kernel(const float* __restrict__ rs, const float* __restrict__ rc,
                             const float* __restrict__ ls, const float* __restrict__ lc,
                             const float* __restrict__ fcW, const float* __restrict__ fcb,
                             float* __restrict__ out) {
    int b = blockIdx.x * blockDim.x + threadIdx.x;
    if (b >= N_GRAPHS) return;
    float hc[2 * D];
    float rn = fmaxf(rc[b], 1.f), ln = fmaxf(lc[b], 1.f);
#pragma unroll
    for (int j = 0; j < D; j++) {
        hc[j]     = rs[b * D + j] / rn;
        hc[D + j] = ls[b * D + j] / ln;
    }
#pragma unroll
    for (int c = 0; c < 6; c++) {
        float acc = fcb[c];
#pragma unroll
        for (int j = 0; j < 2 * D; j++) acc += hc[j] * fcW[c * 2 * D + j];
        if (c < 3) out[b * 3 + c] = acc;
        else       out[N_GRAPHS * 3 + b * 3 + (c - 3)] = acc;
    }
}

extern "C" void kernel_launch(void* const* d_in, const int* in_sizes, int n_in,
                              void* d_out, int out_size, void* d_ws, size_t ws_size,
                              hipStream_t stream) {
    const float* emb = (const float*)d_in[0];
    const float* W1  = (const float*)d_in[1];
    const float* b1  = (const float*)d_in[2];
    const float* W2  = (const float*)d_in[3];
    const float* b2  = (const float*)d_in[4];
    const float* fcW = (const float*)d_in[5];
    const float* fcb = (const float*)d_in[6];
    const int* rx = (const int*)d_in[7];
    const int* re = (const int*)d_in[8];
    const int* rb = (const int*)d_in[9];
    const int* lx = (const int*)d_in[10];
    const int* le = (const int*)d_in[11];
    const int* lb = (const int*)d_in[12];
    float* out = (float*)d_out;

    char* w = (char*)d_ws;
    unsigned int* slabR = (unsigned int*)w;    w += (size_t)NBUK * CAP * 4;
    unsigned int* slabL = (unsigned int*)w;    w += (size_t)NBUK * CAP * 4;
    __hip_bfloat16* hs1R = (__hip_bfloat16*)w; w += (size_t)N_NODES * D * 2;
    __hip_bfloat16* hs1L = (__hip_bfloat16*)w; w += (size_t)N_NODES * D * 2;
    __hip_bfloat16* hs2R = (__hip_bfloat16*)w; w += (size_t)N_NODES * D * 2;
    __hip_bfloat16* hs2L = (__hip_bfloat16*)w; w += (size_t)N_NODES * D * 2;
    int2* metaR = (int2*)w;                    w += (size_t)N_NODES * 8;
    int2* metaL = (int2*)w;                    w += (size_t)N_NODES * 8;
    float* disR = (float*)w;                   w += (size_t)N_NODES * 4;
    float* disL = (float*)w;                   w += (size_t)N_NODES * 4;
    // zero-init region: gcurR, gcurL, sums0, cnt0, sums1, cnt1 (single memset)
    char* zbase = w;
    int* gcurR = (int*)w;                      w += (size_t)NBUK * 4;
    int* gcurL = (int*)w;                      w += (size_t)NBUK * 4;
    float* sums0 = (float*)w;                  w += (size_t)N_GRAPHS * D * 4;
    float* cnt0  = (float*)w;                  w += (size_t)N_GRAPHS * 4;
    float* sums1 = (float*)w;                  w += (size_t)N_GRAPHS * D * 4;
    float* cnt1  = (float*)w;                  w += (size_t)N_GRAPHS * 4;
    size_t zsize = (size_t)(w - zbase);

    const int* srcR = re;  const int* dstR = re + NEDGE;
    const int* srcL = le;  const int* dstL = le + NEDGE;

    hipMemsetAsync(zbase, 0, zsize, stream);

    // ---- CSR build: direct-append (bucket-grouped) + in-place per-bucket sort ----
    pA<<<dim3(NCH, 2), 1024, 0, stream>>>(srcR, dstR, srcL, dstL,
                                          slabR, slabL, gcurR, gcurL);
    pB2<<<dim3(NBUK, 2), 256, 0, stream>>>(slabR, slabL, gcurR, gcurL,
                                           metaR, metaL, disR, disL);

    // ---- fused GCN pipeline ----
    t1_kernel<<<dim3(GBLK, 2), 256, 0, stream>>>(rx, lx, emb, W1, disR, disL, hs1R, hs1L);
    g1_kernel<<<2 * GHALF, 256, 0, stream>>>(metaR, metaL, slabR, slabL,
                                             hs1R, hs1L, disR, disL, b1, W2, hs2R, hs2L);
    g2_kernel<<<2 * GHALF, 256, 0, stream>>>(metaR, metaL, slabR, slabL,
                                             hs2R, hs2L, disR, disL, b2, rb, lb,
                                             sums0, sums1, cnt0, cnt1);
    final_kernel<<<(N_GRAPHS + 255) / 256, 256, 0, stream>>>(
        sums0, cnt0, sums1, cnt1, fcW, fcb, out);
}

// Round 5
// 513.310 us; speedup vs baseline: 5.1027x; 1.0343x over previous
//
#include <hip/hip_runtime.h>
#include <hip/hip_bf16.h>

#define N_NODES 200000
#define N_GRAPHS 1024
#define D 16
#define NEDGE 6400000

#define BNODES 256                 // nodes per bucket: bucket = dst >> 8
#define NBUK 782                   // ceil(200000/256)
#define NCH 640                    // edge chunks
#define ECHUNK 10000               // NEDGE / NCH (exact)
#define CAP 9216                   // bucket slab capacity (mean 8192, sd ~90 -> 11 sigma)
#define GHALF 6250                 // gather blocks per protein: 32 nodes x 8 lanes

// ---- pA (fused R+L): sort one 10000-edge chunk by bucket in LDS, then append each
//      bucket-run directly into the global per-bucket slab (atomic run allocation,
//      coalesced run writes). Output: bucket-grouped, unsorted within bucket. ----
__global__ __launch_bounds__(1024) void pA(
        const int* __restrict__ srcR, const int* __restrict__ dstR,
        const int* __restrict__ srcL, const int* __restrict__ dstL,
        unsigned int* __restrict__ slabR, unsigned int* __restrict__ slabL,
        int* __restrict__ gcurR, int* __restrict__ gcurL) {
    const int* src = blockIdx.y ? srcL : srcR;
    const int* dst = blockIdx.y ? dstL : dstR;
    unsigned int* slab = blockIdx.y ? slabL : slabR;
    int* gcur = blockIdx.y ? gcurL : gcurR;

    __shared__ unsigned int stage[ECHUNK];      // 40 KB
    __shared__ unsigned short stageB[ECHUNK];   // 20 KB (bucket id per staged entry)
    __shared__ int lh[NBUK];                    // counts -> append offset (gb - excl)
    __shared__ int lcur[NBUK];
    __shared__ int wsum[16];
    int t = threadIdx.x;
    int wave = t >> 6, lane = t & 63;
    int base = blockIdx.x * ECHUNK;

    for (int k = t; k < NBUK; k += 1024) lh[k] = 0;
    __syncthreads();
    for (int e = t; e < ECHUNK; e += 1024)
        atomicAdd(&lh[((unsigned int)dst[base + e]) >> 8], 1);
    __syncthreads();

    int v = (t < NBUK) ? lh[t] : 0;
    int x = v;
#pragma unroll
    for (int d0 = 1; d0 < 64; d0 <<= 1) {
        int y = __shfl_up(x, d0, 64);
        if (lane >= d0) x += y;
    }
    if (lane == 63) wsum[wave] = x;
    __syncthreads();
    if (wave == 0 && lane < 16) {
        int s = wsum[lane];
#pragma unroll
        for (int d0 = 1; d0 < 16; d0 <<= 1) {
            int y = __shfl_up(s, d0, 64);
            if (lane >= d0) s += y;
        }
        wsum[lane] = s;
    }
    __syncthreads();
    int excl = x - v + (wave ? wsum[wave - 1] : 0);
    if (t < NBUK) lcur[t] = excl;
    __syncthreads();
    // allocate this chunk's run in each bucket's global slab region
    if (t < NBUK) {
        int gb = v ? atomicAdd(&gcur[t], v) : 0;
        lh[t] = gb - excl;                      // global offset = lh[buk] + staged_pos
    }
    __syncthreads();

    for (int e = t; e < ECHUNK; e += 1024) {
        int d = dst[base + e];
        int s = src[base + e];
        int buk = ((unsigned int)d) >> 8;
        int pos = atomicAdd(&lcur[buk], 1);
        stage[pos] = ((unsigned int)(d & 255) << 18) | (unsigned int)s;
        stageB[pos] = (unsigned short)buk;
    }
    __syncthreads();
    for (int e = t; e < ECHUNK; e += 1024) {
        int k = stageB[e];
        int off = lh[k] + e;                    // gb + (e - excl[k])
        slab[(size_t)k * CAP + off] = stage[e];
    }
}

// ---- pB2 (512 thr, 41 KB LDS -> 3 blocks/CU): in-place per-bucket counting sort
//      from coalesced slab reads (count pass + cache-hot place pass), FUSED with
//      the t1 transform epilogue: hs1[i,:] = bf16((emb[ids[i]] @ W1) * dis[i]) ----
__global__ __launch_bounds__(512) void pB2(
        unsigned int* __restrict__ slabR, unsigned int* __restrict__ slabL,
        const int* __restrict__ gcurR, const int* __restrict__ gcurL,
        const int* __restrict__ idsR, const int* __restrict__ idsL,
        const float* __restrict__ emb, const float* __restrict__ W1,
        int2* __restrict__ metaR, int2* __restrict__ metaL,
        float* __restrict__ disR, float* __restrict__ disL,
        __hip_bfloat16* __restrict__ hs1R, __hip_bfloat16* __restrict__ hs1L) {
    int y = blockIdx.y;
    unsigned int* slab = y ? slabL : slabR;
    const int* gcur = y ? gcurL : gcurR;
    const int* ids = y ? idsL : idsR;
    int2* meta = y ? metaL : metaR;
    float* dis = y ? disL : disR;
    __hip_bfloat16* hs1 = y ? hs1L : hs1R;

    __shared__ unsigned int sout[CAP];       // 36.9 KB
    __shared__ int hcnt[BNODES], hoff[BNODES], hcur[BNODES];
    __shared__ float sW[D][D];
    __shared__ int wtot[4];
    int t = threadIdx.x;
    int b = blockIdx.x;
    if (t < 256) { sW[t >> 4][t & 15] = W1[t]; hcnt[t] = 0; }
    int cnt = gcur[b]; if (cnt > CAP) cnt = CAP;   // statistically unreachable
    unsigned int* sl = slab + (size_t)b * CAP;
    __syncthreads();

    // count (coalesced stream read #1)
    for (int i = t; i < cnt; i += 512)
        atomicAdd(&hcnt[sl[i] >> 18], 1);
    __syncthreads();

    // exclusive scan of hcnt (first 4 waves)
    int lane = t & 63, wave = t >> 6;
    int v2 = (t < 256) ? hcnt[t] : 0;
    int x2 = v2;
#pragma unroll
    for (int d0 = 1; d0 < 64; d0 <<= 1) {
        int yy = __shfl_up(x2, d0, 64);
        if (lane >= d0) x2 += yy;
    }
    if (t < 256 && lane == 63) wtot[wave] = x2;
    __syncthreads();
    if (t < 256) {
        int pre2 = 0;
        for (int w2 = 0; w2 < wave; w2++) pre2 += wtot[w2];
        int ex = x2 - v2 + pre2;
        hoff[t] = ex;
        hcur[t] = ex;
    }
    __syncthreads();

    // place (read #2 - L1/L2 hot: same 36 KB this block just streamed)
    for (int i = t; i < cnt; i += 512) {
        unsigned int r = sl[i];
        int pp = atomicAdd(&hcur[r >> 18], 1);
        if (pp < CAP) sout[pp] = r & 0x3FFFFu;
    }
    __syncthreads();

    // in-place sorted writeback
    for (int i = t; i < cnt; i += 512) sl[i] = sout[i];   // coalesced

    // epilogue: meta/dis + fused t1 (2 threads per node, 8 feats each)
    int tt = t >> 1, hf = t & 1;
    int node = (b << 8) + tt;
    if (node < N_NODES) {
        int hc = hcnt[tt];
        float di = rsqrtf((float)hc + 1.0f);
        int gb = b * CAP;
        if (hf == 0) {
            meta[node] = make_int2(gb + hoff[tt], gb + hoff[tt] + hc);
            dis[node] = di;
        }
        const float4* er = (const float4*)(emb + (size_t)ids[node] * D);
        float4 e0 = er[0], e1 = er[1], e2 = er[2], e3 = er[3];
        float ex_[D] = {e0.x, e0.y, e0.z, e0.w, e1.x, e1.y, e1.z, e1.w,
                        e2.x, e2.y, e2.z, e2.w, e3.x, e3.y, e3.z, e3.w};
        int j0 = hf * 8;
        float o[8];
#pragma unroll
        for (int jj = 0; jj < 8; jj++) {
            float a = 0.f;
#pragma unroll
            for (int k = 0; k < D; k++) a += ex_[k] * sW[k][j0 + jj];
            o[jj] = a * di;
        }
        uint4 ov;
        __hip_bfloat162* q = (__hip_bfloat162*)&ov;
#pragma unroll
        for (int jj = 0; jj < 4; jj++)
            q[jj] = __float22bfloat162_rn(make_float2(o[2 * jj], o[2 * jj + 1]));
        *(uint4*)(hs1 + (size_t)node * D + j0) = ov;
    }
}

// ---- G1: gather layer1 + relu + transform2 -> hs2. 32 nodes/block, 8 lanes/node. ----
__global__ __launch_bounds__(256) void g1_kernel(
        const int2* __restrict__ metaR, const int2* __restrict__ metaL,
        const unsigned int* __restrict__ csrR, const unsigned int* __restrict__ csrL,
        const __hip_bfloat16* __restrict__ hs1R, const __hip_bfloat16* __restrict__ hs1L,
        const float* __restrict__ disR, const float* __restrict__ disL,
        const float* __restrict__ b1, const float* __restrict__ W2,
        __hip_bfloat16* __restrict__ hs2R, __hip_bfloat16* __restrict__ hs2L) {
    int half = (blockIdx.x >= GHALF);
    int bx = blockIdx.x - (half ? GHALF : 0);
    const int2* meta = half ? metaL : metaR;
    const unsigned int* csr = half ? csrL : csrR;
    const __hip_bfloat16* hs1 = half ? hs1L : hs1R;
    const float* dis = half ? disL : disR;
    __hip_bfloat16* hs2 = half ? hs2L : hs2R;

    __shared__ float sW[D][D];
    __shared__ float sx[32][D + 1];
    int t = threadIdx.x;
    int jp = t & 7, g = t >> 3;
    sW[t >> 4][t & 15] = W2[t];
    int i = (bx << 5) + g;
    int2 be = meta[i];
    float2 acc = __bfloat1622float2(
        *(const __hip_bfloat162*)(hs1 + (size_t)i * D + 2 * jp));
    int e = be.x, end = be.y;
    for (; e + 8 <= end; e += 8) {
        int my = (int)csr[e + jp];
#pragma unroll
        for (int n = 0; n < 8; n++) {
            int s = __shfl(my, n, 8);
            float2 f = __bfloat1622float2(
                *(const __hip_bfloat162*)(hs1 + (size_t)s * D + 2 * jp));
            acc.x += f.x; acc.y += f.y;
        }
    }
    for (; e < end; e++) {
        int s = csr[e];
        float2 f = __bfloat1622float2(
            *(const __hip_bfloat162*)(hs1 + (size_t)s * D + 2 * jp));
        acc.x += f.x; acc.y += f.y;
    }
    float di = dis[i];
    sx[g][2 * jp]     = fmaxf(acc.x * di + b1[2 * jp], 0.f);
    sx[g][2 * jp + 1] = fmaxf(acc.y * di + b1[2 * jp + 1], 0.f);
    __syncthreads();
    float a0 = 0.f, a1 = 0.f;
#pragma unroll
    for (int k = 0; k < D; k++) {
        float xv = sx[g][k];
        a0 += xv * sW[k][2 * jp];
        a1 += xv * sW[k][2 * jp + 1];
    }
    *(__hip_bfloat162*)(hs2 + (size_t)i * D + 2 * jp) =
        __float22bfloat162_rn(make_float2(a0 * di, a1 * di));
}

// ---- G2: gather layer2 + fused mean-pool partial reduction ----
__global__ __launch_bounds__(256) void g2_kernel(
        const int2* __restrict__ metaR, const int2* __restrict__ metaL,
        const unsigned int* __restrict__ csrR, const unsigned int* __restrict__ csrL,
        const __hip_bfloat16* __restrict__ hs2R, const __hip_bfloat16* __restrict__ hs2L,
        const float* __restrict__ disR, const float* __restrict__ disL,
        const float* __restrict__ b2,
        const int* __restrict__ batR, const int* __restrict__ batL,
        float* __restrict__ sumsR, float* __restrict__ sumsL,
        float* __restrict__ cntR, float* __restrict__ cntL) {
    int half = (blockIdx.x >= GHALF);
    int bx = blockIdx.x - (half ? GHALF : 0);
    const int2* meta = half ? metaL : metaR;
    const unsigned int* csr = half ? csrL : csrR;
    const __hip_bfloat16* hs2 = half ? hs2L : hs2R;
    const float* dis = half ? disL : disR;
    const int* batch = half ? batL : batR;
    float* sums = half ? sumsL : sumsR;
    float* cnt = half ? cntL : cntR;

    __shared__ float sv[32][D + 1];
    __shared__ int sb[32];
    int t = threadIdx.x;
    int jp = t & 7, g = t >> 3;
    int i = (bx << 5) + g;
    int2 be = meta[i];
    float2 acc = __bfloat1622float2(
        *(const __hip_bfloat162*)(hs2 + (size_t)i * D + 2 * jp));
    int e = be.x, end = be.y;
    for (; e + 8 <= end; e += 8) {
        int my = (int)csr[e + jp];
#pragma unroll
        for (int n = 0; n < 8; n++) {
            int s = __shfl(my, n, 8);
            float2 f = __bfloat1622float2(
                *(const __hip_bfloat162*)(hs2 + (size_t)s * D + 2 * jp));
            acc.x += f.x; acc.y += f.y;
        }
    }
    for (; e < end; e++) {
        int s = csr[e];
        float2 f = __bfloat1622float2(
            *(const __hip_bfloat162*)(hs2 + (size_t)s * D + 2 * jp));
        acc.x += f.x; acc.y += f.y;
    }
    float di = dis[i];
    int bi = batch[i];
    sv[g][2 * jp]     = acc.x * di + b2[2 * jp];
    sv[g][2 * jp + 1] = acc.y * di + b2[2 * jp + 1];
    if (jp == 0) sb[g] = bi;
    __syncthreads();
    bool runend = (g == 31) || (sb[g + 1] != bi);
    if (runend) {
        float s0 = 0.f, s1 = 0.f;
        int gg = g;
        while (gg >= 0 && sb[gg] == bi) { s0 += sv[gg][2 * jp]; s1 += sv[gg][2 * jp + 1]; gg--; }
        atomicAdd(&sums[bi * D + 2 * jp], s0);
        atomicAdd(&sums[bi * D + 2 * jp + 1], s1);
        if (jp == 0) atomicAdd(&cnt[bi], (float)(g - gg));
    }
}

// ---- final FC ----
__global__ void final_kernel(const float* __restrict__ rs, const float* __restrict__ rc,
                             const float* __restrict__ ls, const float* __restrict__ lc,
                             const float* __restrict__ fcW, const float* __restrict__ fcb,
                             float* __restrict__ out) {
    int b = blockIdx.x * blockDim.x + threadIdx.x;
    if (b >= N_GRAPHS) return;
    float hc[2 * D];
    float rn = fmaxf(rc[b], 1.f), ln = fmaxf(lc[b], 1.f);
#pragma unroll
    for (int j = 0; j < D; j++) {
        hc[j]     = rs[b * D + j] / rn;
        hc[D + j] = ls[b * D + j] / ln;
    }
#pragma unroll
    for (int c = 0; c < 6; c++) {
        float acc = fcb[c];
#pragma unroll
        for (int j = 0; j < 2 * D; j++) acc += hc[j] * fcW[c * 2 * D + j];
        if (c < 3) out[b * 3 + c] = acc;
        else       out[N_GRAPHS * 3 + b * 3 + (c - 3)] = acc;
    }
}

extern "C" void kernel_launch(void* const* d_in, const int* in_sizes, int n_in,
                              void* d_out, int out_size, void* d_ws, size_t ws_size,
                              hipStream_t stream) {
    const float* emb = (const float*)d_in[0];
    const float* W1  = (const float*)d_in[1];
    const float* b1  = (const float*)d_in[2];
    const float* W2  = (const float*)d_in[3];
    const float* b2  = (const float*)d_in[4];
    const float* fcW = (const float*)d_in[5];
    const float* fcb = (const float*)d_in[6];
    const int* rx = (const int*)d_in[7];
    const int* re = (const int*)d_in[8];
    const int* rb = (const int*)d_in[9];
    const int* lx = (const int*)d_in[10];
    const int* le = (const int*)d_in[11];
    const int* lb = (const int*)d_in[12];
    float* out = (float*)d_out;

    char* w = (char*)d_ws;
    unsigned int* slabR = (unsigned int*)w;    w += (size_t)NBUK * CAP * 4;
    unsigned int* slabL = (unsigned int*)w;    w += (size_t)NBUK * CAP * 4;
    __hip_bfloat16* hs1R = (__hip_bfloat16*)w; w += (size_t)N_NODES * D * 2;
    __hip_bfloat16* hs1L = (__hip_bfloat16*)w; w += (size_t)N_NODES * D * 2;
    __hip_bfloat16* hs2R = (__hip_bfloat16*)w; w += (size_t)N_NODES * D * 2;
    __hip_bfloat16* hs2L = (__hip_bfloat16*)w; w += (size_t)N_NODES * D * 2;
    int2* metaR = (int2*)w;                    w += (size_t)N_NODES * 8;
    int2* metaL = (int2*)w;                    w += (size_t)N_NODES * 8;
    float* disR = (float*)w;                   w += (size_t)N_NODES * 4;
    float* disL = (float*)w;                   w += (size_t)N_NODES * 4;
    // zero-init region: gcurR, gcurL, sums0, cnt0, sums1, cnt1 (single memset)
    char* zbase = w;
    int* gcurR = (int*)w;                      w += (size_t)NBUK * 4;
    int* gcurL = (int*)w;                      w += (size_t)NBUK * 4;
    float* sums0 = (float*)w;                  w += (size_t)N_GRAPHS * D * 4;
    float* cnt0  = (float*)w;                  w += (size_t)N_GRAPHS * 4;
    float* sums1 = (float*)w;                  w += (size_t)N_GRAPHS * D * 4;
    float* cnt1  = (float*)w;                  w += (size_t)N_GRAPHS * 4;
    size_t zsize = (size_t)(w - zbase);

    const int* srcR = re;  const int* dstR = re + NEDGE;
    const int* srcL = le;  const int* dstL = le + NEDGE;

    hipMemsetAsync(zbase, 0, zsize, stream);

    // ---- CSR build: direct-append (bucket-grouped) + in-place sort (+fused t1) ----
    pA<<<dim3(NCH, 2), 1024, 0, stream>>>(srcR, dstR, srcL, dstL,
                                          slabR, slabL, gcurR, gcurL);
    pB2<<<dim3(NBUK, 2), 512, 0, stream>>>(slabR, slabL, gcurR, gcurL,
                                           rx, lx, emb, W1,
                                           metaR, metaL, disR, disL, hs1R, hs1L);

    // ---- fused GCN pipeline ----
    g1_kernel<<<2 * GHALF, 256, 0, stream>>>(metaR, metaL, slabR, slabL,
                                             hs1R, hs1L, disR, disL, b1, W2, hs2R, hs2L);
    g2_kernel<<<2 * GHALF, 256, 0, stream>>>(metaR, metaL, slabR, slabL,
                                             hs2R, hs2L, disR, disL, b2, rb, lb,
                                             sums0, sums1, cnt0, cnt1);
    final_kernel<<<(N_GRAPHS + 255) / 256, 256, 0, stream>>>(
        sums0, cnt0, sums1, cnt1, fcW, fcb, out);
}